// Round 7
// baseline (311.378 us; speedup 1.0000x reference)
//
#include <hip/hip_runtime.h>
#include <stdint.h>

// B=4, S=2048, D=1024, H=16, DK=64. fp32 in/out, bf16 MFMA internal.
// Pipeline:
//   0) cvt_w: Wq,Wk,Wv,Wp fp32 -> bf16.  0b) cvt_in: q,k,v fp32 -> bf16
//      (qb2/kb2 in d_out scratch; vb2 in ws when ws_size allows).
//   1) gemm_qkv8: 256x128-tile, BK=64, 8-wave, triple-buffered LDS with
//      counted vmcnt(6) + one barrier per K-tile + T2 XOR-swizzle.
//      grid (32,8,3) = 768 blocks. Q pre-scaled by 0.125*log2e; V -> Vt.
//   2) attn: flash causal, XCD-local + causal-balanced, swapped QK^T with
//      fully in-register P. NEW: 2x2 WAVE SPLIT -- wave (wq,wk) owns q-rows
//      [wq*32,+32) x keys [wk*32,+32), halving the per-wave K/V fragment
//      reads (all 4 waves previously read IDENTICAL fragments; LDS pipe was
//      ~74% busy = the binding resource). Cross-wk O/lsum reduction once
//      per segment through 16KB LDS scratch.
//   3) gemm_proj8: same pipelined core, grid (32,8).

#define SZB (8192u * 1024u * 2u)   // one [8192][1024] bf16 buffer (16 MB)
#define WSZ (1024u * 1024u * 2u)   // one [1024][1024] bf16 weight (2 MB)
#define NKT 16                     // K=1024 / BK=64
#define SLOT 24576                 // ushorts per LDS slot: A 16384 + B 8192

typedef __attribute__((ext_vector_type(8))) short  short8;
typedef __attribute__((ext_vector_type(4))) short  short4v;
typedef __attribute__((ext_vector_type(4))) float  f32x4;

#define MFMA16(a, b, c) __builtin_amdgcn_mfma_f32_16x16x32_bf16(a, b, c, 0, 0, 0)

// K=16 MFMA: A/B = 4 bf16 in 2 VGPRs; lane (quad,l16) holds A[m=l16][k=quad*4+j].
__device__ __forceinline__ f32x4 mfma_k16(short4v a, short4v b, f32x4 c) {
#if __has_builtin(__builtin_amdgcn_mfma_f32_16x16x16bf16_1k)
  return __builtin_amdgcn_mfma_f32_16x16x16bf16_1k(a, b, c, 0, 0, 0);
#else
  asm volatile("v_mfma_f32_16x16x16_bf16 %0, %1, %2, %0"
               : "+v"(c) : "v"(a), "v"(b));
  return c;
#endif
}
// pack two f32 -> one u32 of 2 bf16 (lo = a, hi = b), RNE
__device__ __forceinline__ uint32_t cvtpk(float a, float b) {
  uint32_t r;
  asm("v_cvt_pk_bf16_f32 %0, %1, %2" : "=v"(r) : "v"(a), "v"(b));
  return r;
}

__device__ __forceinline__ ushort f2bf(float f) {
  uint32_t u = __float_as_uint(f);
  u += 0x7FFF + ((u >> 16) & 1);   // RNE
  return (ushort)(u >> 16);
}
__device__ __forceinline__ short8 cvt8(float4 a, float4 b) {
  short8 r;
  r[0] = (short)f2bf(a.x); r[1] = (short)f2bf(a.y);
  r[2] = (short)f2bf(a.z); r[3] = (short)f2bf(a.w);
  r[4] = (short)f2bf(b.x); r[5] = (short)f2bf(b.y);
  r[6] = (short)f2bf(b.z); r[7] = (short)f2bf(b.w);
  return r;
}
// async global -> LDS, 16B/lane; LDS dest = wave-uniform base + lane*16
__device__ __forceinline__ void gl_lds16(const ushort* g, ushort* l) {
  __builtin_amdgcn_global_load_lds(
      (__attribute__((address_space(1))) void*)g,
      (__attribute__((address_space(3))) void*)l, 16, 0, 0);
}

// ---------------------------------------------------------------------------
// Weight conversion: 4 x [1024][1024] fp32 -> bf16. grid (512, 4).
// ---------------------------------------------------------------------------
__global__ __launch_bounds__(256) void cvt_w(
    const float* __restrict__ Wq, const float* __restrict__ Wk,
    const float* __restrict__ Wv, const float* __restrict__ Wp,
    ushort* __restrict__ Wqb, ushort* __restrict__ Wkb,
    ushort* __restrict__ Wvb, ushort* __restrict__ Wpb) {
  const int z = blockIdx.y;
  const float* s = (z == 0) ? Wq : (z == 1) ? Wk : (z == 2) ? Wv : Wp;
  ushort* d = (z == 0) ? Wqb : (z == 1) ? Wkb : (z == 2) ? Wvb : Wpb;
  const size_t i = (size_t)(blockIdx.x * 256 + threadIdx.x) * 8;
  *(short8*)&d[i] = cvt8(*(const float4*)&s[i], *(const float4*)&s[i + 4]);
}

// ---------------------------------------------------------------------------
// Input conversion: q,k,v [4,2048,1024] fp32 -> bf16. grid (4096, 2 or 3).
// ---------------------------------------------------------------------------
__global__ __launch_bounds__(256) void cvt_in(
    const float* __restrict__ q, const float* __restrict__ k,
    const float* __restrict__ v,
    ushort* __restrict__ qb2, ushort* __restrict__ kb2,
    ushort* __restrict__ vb2) {
  const int z = blockIdx.y;
  const float* s = (z == 0) ? q : (z == 1) ? k : v;
  ushort* d = (z == 0) ? qb2 : (z == 1) ? kb2 : vb2;
  const size_t i = (size_t)(blockIdx.x * 256 + threadIdx.x) * 8;
  *(short8*)&d[i] = cvt8(*(const float4*)&s[i], *(const float4*)&s[i + 4]);
}

// ---------------------------------------------------------------------------
// 8-wave triple-buffered core: C = A[M,K]bf16 * W[N,K]bf16^T.
// BM=256, BN=128, BK=64. 512 threads = 8 waves as 4M x 2N; per-wave 64x64.
// XOR-swizzled LDS (linear gl_lds dest, inverse-swizzled global source,
// swizzled ds_read). Schedule per K-tile: {vmcnt(6); barrier; stage(j+2);
// compute} -- counted vmcnt, never 0 in-loop.
// ---------------------------------------------------------------------------
__device__ __forceinline__ void core8p(
    const ushort* __restrict__ A, const ushort* __restrict__ Wb,
    ushort* lds, int m0, int n0, f32x4 acc[4][4]) {
  const int tid  = threadIdx.x;
  const int w    = tid >> 6;
  const int lane = tid & 63;
  const int quad = lane >> 4;
  const int l16  = lane & 15;
  const int wm   = (w >> 1) * 64;   // 4 M-waves
  const int wn   = (w & 1) * 64;    // 2 N-waves

  const ushort* asrc[4];
  const ushort* bsrc[2];
#pragma unroll
  for (int i = 0; i < 4; ++i) {
    const int c = tid + 512 * i;
    asrc[i] = A + (size_t)(m0 + (c >> 3)) * 1024 + ((c & 7) ^ ((c >> 3) & 7)) * 8;
  }
#pragma unroll
  for (int i = 0; i < 2; ++i) {
    const int c = tid + 512 * i;
    bsrc[i] = Wb + (size_t)(n0 + (c >> 3)) * 1024 + ((c & 7) ^ ((c >> 3) & 7)) * 8;
  }

  auto stage = [&](int j, int s) {
    ushort* base = lds + s * SLOT + w * 512;
#pragma unroll
    for (int i = 0; i < 4; ++i)
      gl_lds16(asrc[i] + j * 64, base + i * 4096);
#pragma unroll
    for (int i = 0; i < 2; ++i)
      gl_lds16(bsrc[i] + j * 64, base + 16384 + i * 4096);
  };

  const int rsw = (l16 & 7) * 8;   // read-side XOR (row&7 == l16&7 here)
  auto compute = [&](int s) {
    const ushort* pA = lds + s * SLOT;
    const ushort* pB = pA + 16384;
    short8 a[4][2], b[4][2];
#pragma unroll
    for (int f = 0; f < 4; ++f)
#pragma unroll
      for (int ks = 0; ks < 2; ++ks) {
        a[f][ks] = *(const short8*)&pA[(wm + f * 16 + l16) * 64 +
                                       ((ks * 32 + quad * 8) ^ rsw)];
        b[f][ks] = *(const short8*)&pB[(wn + f * 16 + l16) * 64 +
                                       ((ks * 32 + quad * 8) ^ rsw)];
      }
    __builtin_amdgcn_s_setprio(1);
#pragma unroll
    for (int i = 0; i < 4; ++i)
#pragma unroll
      for (int j2 = 0; j2 < 4; ++j2) {
        acc[i][j2] = MFMA16(a[i][0], b[j2][0], acc[i][j2]);
        acc[i][j2] = MFMA16(a[i][1], b[j2][1], acc[i][j2]);
      }
    __builtin_amdgcn_s_setprio(0);
  };

  stage(0, 0);
  stage(1, 1);
  int s = 0;
#pragma unroll 1
  for (int j = 0; j < NKT - 1; ++j) {
    asm volatile("s_waitcnt vmcnt(6)" ::: "memory");
    __builtin_amdgcn_s_barrier();
    __builtin_amdgcn_sched_barrier(0);
    if (j < NKT - 2) {
      int s2 = s + 2; if (s2 >= 3) s2 -= 3;
      stage(j + 2, s2);
    }
    compute(s);
    if (++s == 3) s = 0;
  }
  asm volatile("s_waitcnt vmcnt(0)" ::: "memory");
  __builtin_amdgcn_s_barrier();
  __builtin_amdgcn_sched_barrier(0);
  compute(s);
}

// ---------------------------------------------------------------------------
// QKV projection, pipelined core. grid (32, 8, 3 or 2), 512 threads.
// z==0 -> Qb (pre-scaled by 0.125*log2e), z==1 -> Kb, z==2 -> Vt transposed.
// ---------------------------------------------------------------------------
__global__ __launch_bounds__(512, 2) void gemm_qkv8(
    const ushort* __restrict__ qb2, const ushort* __restrict__ kb2,
    const ushort* __restrict__ vb2,
    const ushort* __restrict__ Wqb, const ushort* __restrict__ Wkb,
    const ushort* __restrict__ Wvb,
    const float* __restrict__ bq, const float* __restrict__ bk,
    const float* __restrict__ bv,
    ushort* __restrict__ Qb, ushort* __restrict__ Kb, ushort* __restrict__ Vt) {
  __shared__ ushort lds[3 * SLOT];   // 144 KB

  const int z = blockIdx.z;
  const ushort* A    = (z == 0) ? qb2 : (z == 1) ? kb2 : vb2;
  const ushort* W    = (z == 0) ? Wqb : (z == 1) ? Wkb : Wvb;
  const float*  bias = (z == 0) ? bq  : (z == 1) ? bk  : bv;

  const int m0 = blockIdx.x * 256;
  const int n0 = blockIdx.y * 128;

  f32x4 acc[4][4] = {};
  core8p(A, W, lds, m0, n0, acc);

  const int tid  = threadIdx.x;
  const int w    = tid >> 6;
  const int lane = tid & 63;
  const int quad = lane >> 4;
  const int l16  = lane & 15;
  const int wm   = (w >> 1) * 64;
  const int wn   = (w & 1) * 64;

  float bvv[4];
#pragma unroll
  for (int j = 0; j < 4; ++j) bvv[j] = bias[n0 + wn + j * 16 + l16];

  if (z < 2) {
    ushort* Out = (z == 0) ? Qb : Kb;
    const float sc = (z == 0) ? 0.1803368801f : 1.0f;  // 0.125*log2(e) for Q
#pragma unroll
    for (int i = 0; i < 4; ++i) {
      const int m = m0 + wm + i * 16 + quad * 4;
#pragma unroll
      for (int j = 0; j < 4; ++j) {
        const int n = n0 + wn + j * 16 + l16;
#pragma unroll
        for (int r = 0; r < 4; ++r)
          Out[(size_t)(m + r) * 1024 + n] = f2bf((acc[i][j][r] + bvv[j]) * sc);
      }
    }
  } else {
#pragma unroll
    for (int i = 0; i < 4; ++i) {
      const int mrow = m0 + wm + i * 16 + quad * 4;
      const int bb   = mrow >> 11;
      const int s0   = mrow & 2047;
#pragma unroll
      for (int j = 0; j < 4; ++j) {
        const int n = n0 + wn + j * 16 + l16;        // n = h*64 + dk
        ushort4 pk;
        pk.x = f2bf(acc[i][j][0] + bvv[j]);
        pk.y = f2bf(acc[i][j][1] + bvv[j]);
        pk.z = f2bf(acc[i][j][2] + bvv[j]);
        pk.w = f2bf(acc[i][j][3] + bvv[j]);
        *(ushort4*)&Vt[(size_t)((bb * 16 + (n >> 6)) * 64 + (n & 63)) * 2048 + s0] = pk;
      }
    }
  }
}

// ---------------------------------------------------------------------------
// Output projection, pipelined core: out = X @ Wp^T + bp, fp32. grid (32, 8).
// ---------------------------------------------------------------------------
__global__ __launch_bounds__(512, 2) void gemm_proj8(
    const ushort* __restrict__ Xin, const ushort* __restrict__ Wpb,
    const float* __restrict__ bp, float* __restrict__ Out) {
  __shared__ ushort lds[3 * SLOT];

  const int m0 = blockIdx.x * 256;
  const int n0 = blockIdx.y * 128;

  f32x4 acc[4][4] = {};
  core8p(Xin, Wpb, lds, m0, n0, acc);

  const int tid  = threadIdx.x;
  const int w    = tid >> 6;
  const int lane = tid & 63;
  const int quad = lane >> 4;
  const int l16  = lane & 15;
  const int wm   = (w >> 1) * 64;
  const int wn   = (w & 1) * 64;

  float bvv[4];
#pragma unroll
  for (int j = 0; j < 4; ++j) bvv[j] = bp[n0 + wn + j * 16 + l16];

#pragma unroll
  for (int i = 0; i < 4; ++i) {
    const int m = m0 + wm + i * 16 + quad * 4;
#pragma unroll
    for (int j = 0; j < 4; ++j) {
      const int n = n0 + wn + j * 16 + l16;
#pragma unroll
      for (int r = 0; r < 4; ++r)
        Out[(size_t)(m + r) * 1024 + n] = acc[i][j][r] + bvv[j];
    }
  }
}

// ---------------------------------------------------------------------------
// Fallback V projection (mixed fp32 core), used only when ws can't hold vb2.
// ---------------------------------------------------------------------------
__global__ __launch_bounds__(256) void gemm_v_fb(
    const float* __restrict__ vin, const ushort* __restrict__ Wvb,
    const float* __restrict__ bv, ushort* __restrict__ Vt) {
  __shared__ ushort As[128 * 32];
  __shared__ ushort Bs[128 * 32];

  const int tid  = threadIdx.x;
  const int w    = tid >> 6;
  const int lane = tid & 63;
  const int quad = lane >> 4;
  const int l16  = lane & 15;
  const int wm   = (w >> 1) * 64;
  const int wn   = (w & 1) * 64;
  const int r0   = tid >> 2;
  const int r1   = r0 + 64;
  const int c0   = (tid & 3) * 8;

  const int m0 = blockIdx.x * 128;
  const int n0 = blockIdx.y * 128;

  f32x4 acc[4][4] = {};
  const ushort* Wg = Wvb + (size_t)(n0 + w * 32 + (lane >> 2)) * 1024 + (lane & 3) * 8;
  const float*  Ag0 = vin + (size_t)(m0 + r0) * 1024 + c0;
  const float*  Ag1 = vin + (size_t)(m0 + r1) * 1024 + c0;

  float4 p0a = *(const float4*)(Ag0), p0b = *(const float4*)(Ag0 + 4);
  float4 p1a = *(const float4*)(Ag1), p1b = *(const float4*)(Ag1 + 4);

  for (int kt = 0; kt < 32; ++kt) {
    const int ko = kt * 32;
    __syncthreads();
    *(short8*)&As[r0 * 32 + c0] = cvt8(p0a, p0b);
    *(short8*)&As[r1 * 32 + c0] = cvt8(p1a, p1b);
    gl_lds16(Wg + ko,         &Bs[(w * 32) * 32]);
    gl_lds16(Wg + 16384 + ko, &Bs[(w * 32 + 16) * 32]);
    __syncthreads();
    if (kt < 31) {
      const int kn = ko + 32;
      p0a = *(const float4*)(Ag0 + kn); p0b = *(const float4*)(Ag0 + kn + 4);
      p1a = *(const float4*)(Ag1 + kn); p1b = *(const float4*)(Ag1 + kn + 4);
    }
    short8 af[4], bfr[4];
#pragma unroll
    for (int i = 0; i < 4; ++i)
      af[i] = *(const short8*)&As[(wm + i * 16 + l16) * 32 + quad * 8];
#pragma unroll
    for (int i = 0; i < 4; ++i)
      bfr[i] = *(const short8*)&Bs[(wn + i * 16 + l16) * 32 + quad * 8];
#pragma unroll
    for (int i = 0; i < 4; ++i)
#pragma unroll
      for (int j = 0; j < 4; ++j)
        acc[i][j] = MFMA16(af[i], bfr[j], acc[i][j]);
  }

  float bvv[4];
#pragma unroll
  for (int j = 0; j < 4; ++j) bvv[j] = bv[n0 + wn + j * 16 + l16];
#pragma unroll
  for (int i = 0; i < 4; ++i) {
    const int mrow = m0 + wm + i * 16 + quad * 4;
    const int bb   = mrow >> 11;
    const int s0   = mrow & 2047;
#pragma unroll
    for (int j = 0; j < 4; ++j) {
      const int n = n0 + wn + j * 16 + l16;
      ushort4 pk;
      pk.x = f2bf(acc[i][j][0] + bvv[j]);
      pk.y = f2bf(acc[i][j][1] + bvv[j]);
      pk.z = f2bf(acc[i][j][2] + bvv[j]);
      pk.w = f2bf(acc[i][j][3] + bvv[j]);
      *(ushort4*)&Vt[(size_t)((bb * 16 + (n >> 6)) * 64 + (n & 63)) * 2048 + s0] = pk;
    }
  }
}

// ---------------------------------------------------------------------------
// Flash attention (causal + padding mask). grid (16 pair, 64 bh), 4 waves.
// XCD-local remap + causal balance (block pair: q-tiles pair and 31-pair).
// 2x2 WAVE SPLIT: wave w -> (wq = w>>1, wk = w&1); owns q-rows
// [wq*32,+32) x keys [wk*32,+32) of the 64x64 tile. Swapped QK^T
// (mfma(K,Q)): lane (quad,l16) holds S[key=wk*32+kg*16+quad*4+r]
// [q=wq*32+qc*16+l16] -- exactly the K=16 A-frag layout, so P stays
// in-register. Per-wave LDS frag reads halve (4 b128 K + 8 b64 V vs
// 8 b128 + 16 b64): the LDS pipe was the binding resource (~74% busy).
// Cross-wk O reduction once per segment via 16KB LDS scratch; lsum via
// a 1KB strip. Output in place into Qb.
// ---------------------------------------------------------------------------
__global__ __launch_bounds__(256, 4) void attn(
    ushort* __restrict__ Qb, const ushort* __restrict__ Kb,
    const ushort* __restrict__ Vt, const int* __restrict__ mask) {
  __shared__ ushort Ks[64 * 68];         // [key][dk], padded
  __shared__ ushort Vts[64 * 68];        // [dk][key], padded
  __shared__ f32x4  red[16 * 64];        // O cross-wk scratch (16 KB)
  __shared__ float  sml[2][2][2][16];    // lsum strip [wq][wk][qc][l16]

  const int wgid = (int)blockIdx.x + 16 * (int)blockIdx.y;
  const int xcd  = wgid & 7;
  const int idx  = wgid >> 3;            // 0..127
  const int bh   = xcd * 8 + (idx >> 4); // 8 bh per XCD
  const int pair = idx & 15;
  const int b = bh >> 4, h = bh & 15;
  const int tid = threadIdx.x, w = tid >> 6, lane = tid & 63;
  const int quad = lane >> 4, l16 = lane & 15;
  const int wq = w >> 1, wk = w & 1;     // q-half / key-half of this wave

  short8 kst[2], vst[2];
  int mld;

  auto ld_tile = [&](int k0) {
#pragma unroll
    for (int i = 0; i < 2; ++i) {
      const int c = tid + 256 * i;
      kst[i] = *(const short8*)&Kb[(size_t)(b * 2048 + k0 + (c >> 3)) * 1024 +
                                   h * 64 + (c & 7) * 8];
      vst[i] = *(const short8*)&Vt[(size_t)(bh * 64 + (c >> 3)) * 2048 +
                                   k0 + (c & 7) * 8];
    }
    mld = mask[b * 2048 + k0 + lane];
  };

#pragma unroll 1
  for (int seg = 0; seg < 2; ++seg) {
    const int qt = seg ? (31 - pair) : pair;
    const int q0 = qt * 64;

    // Q B-frags for this wave's 32 q-rows: row = q0 + wq*32 + qc*16 + l16
    short8 qf[2][2];
#pragma unroll
    for (int qc = 0; qc < 2; ++qc) {
      const size_t qoff = (size_t)(b * 2048 + q0 + wq * 32 + qc * 16 + l16) * 1024 +
                          h * 64 + quad * 8;
      qf[qc][0] = *(const short8*)&Qb[qoff];
      qf[qc][1] = *(const short8*)&Qb[qoff + 32];
    }

    f32x4 oacc[2][4] = {};                 // [qc][nb], partial over wk's keys
    float lsum[2] = {0.f, 0.f};            // [qc], partial over wk's keys

    ld_tile(0);

    for (int kt = 0; kt <= qt; ++kt) {
      __syncthreads();   // prior iteration's Ks/Vts readers done
#pragma unroll
      for (int i = 0; i < 2; ++i) {
        const int c = tid + 256 * i;
        *(short8*)&Ks[(c >> 3) * 68 + (c & 7) * 8]  = kst[i];
        *(short8*)&Vts[(c >> 3) * 68 + (c & 7) * 8] = vst[i];
      }
      const int mcur = mld;
      __syncthreads();   // staging visible

      // prefetch next K/V tile: latency hides under QK^T + softmax + PV
      if (kt < qt) ld_tile((kt + 1) * 64);

      const unsigned long long mbits = __ballot(mcur != 0);
      const bool allm = (mbits == ~0ull);

      // scores: sc[kg][qc][r] = S[key=wk*32+kg*16+quad*4+r][q=wq*32+qc*16+l16]
      f32x4 sc[2][2];
#pragma unroll
      for (int kg = 0; kg < 2; ++kg) {
        const short8 kf0 = *(const short8*)&Ks[(wk * 32 + kg * 16 + l16) * 68 + quad * 8];
        const short8 kf1 = *(const short8*)&Ks[(wk * 32 + kg * 16 + l16) * 68 + 32 + quad * 8];
#pragma unroll
        for (int qc = 0; qc < 2; ++qc) {
          f32x4 z4 = {0.f, 0.f, 0.f, 0.f};
          z4 = MFMA16(kf0, qf[qc][0], z4);
          z4 = MFMA16(kf1, qf[qc][1], z4);
          sc[kg][qc] = z4;
        }
      }

      // softmax numerators, in-register
      float pv[2][2][4];
      if (kt < qt && allm) {
#pragma unroll
        for (int kg = 0; kg < 2; ++kg)
#pragma unroll
          for (int qc = 0; qc < 2; ++qc)
#pragma unroll
            for (int r = 0; r < 4; ++r)
              pv[kg][qc][r] = __builtin_amdgcn_exp2f(sc[kg][qc][r]);
      } else if (kt < qt) {
#pragma unroll
        for (int kg = 0; kg < 2; ++kg) {
          const uint32_t sub = (uint32_t)(mbits >> (wk * 32 + kg * 16));
#pragma unroll
          for (int qc = 0; qc < 2; ++qc)
#pragma unroll
            for (int r = 0; r < 4; ++r) {
              const bool ok = (sub >> (quad * 4 + r)) & 1;
              pv[kg][qc][r] = __builtin_amdgcn_exp2f(ok ? sc[kg][qc][r] : -1e5f);
            }
        }
      } else {
#pragma unroll
        for (int kg = 0; kg < 2; ++kg) {
          const uint32_t sub = allm ? 0xffffffffu
                                    : (uint32_t)(mbits >> (wk * 32 + kg * 16));
#pragma unroll
          for (int qc = 0; qc < 2; ++qc)
#pragma unroll
            for (int r = 0; r < 4; ++r) {
              const int kl   = wk * 32 + kg * 16 + quad * 4 + r;  // local key
              const int qlcl = wq * 32 + qc * 16 + l16;           // local q
              const bool ok = (((sub >> (quad * 4 + r)) & 1) != 0) && (kl <= qlcl);
              pv[kg][qc][r] = __builtin_amdgcn_exp2f(ok ? sc[kg][qc][r] : -1e5f);
            }
        }
      }
#pragma unroll
      for (int kg = 0; kg < 2; ++kg)
#pragma unroll
        for (int qc = 0; qc < 2; ++qc)
#pragma unroll
          for (int r = 0; r < 4; ++r) lsum[qc] += pv[kg][qc][r];

      // P -> bf16 A-frags: pa[kg][qc] elem j = P[key=wk*32+kg*16+quad*4+j][q]
      short4v pa[2][2];
#pragma unroll
      for (int kg = 0; kg < 2; ++kg)
#pragma unroll
        for (int qc = 0; qc < 2; ++qc) {
          const uint32_t u0 = cvtpk(pv[kg][qc][0], pv[kg][qc][1]);
          const uint32_t u1 = cvtpk(pv[kg][qc][2], pv[kg][qc][3]);
          pa[kg][qc][0] = (short)(u0 & 0xffff); pa[kg][qc][1] = (short)(u0 >> 16);
          pa[kg][qc][2] = (short)(u1 & 0xffff); pa[kg][qc][3] = (short)(u1 >> 16);
        }

      // O += P.V over this wave's 32 keys (16 x mfma 16x16x16)
#pragma unroll
      for (int kg = 0; kg < 2; ++kg)
#pragma unroll
        for (int nb = 0; nb < 4; ++nb) {
          const short4v vf = *(const short4v*)&Vts[(nb * 16 + l16) * 68 +
                                                   wk * 32 + kg * 16 + quad * 4];
#pragma unroll
          for (int qc = 0; qc < 2; ++qc)
            oacc[qc][nb] = mfma_k16(pa[kg][qc], vf, oacc[qc][nb]);
        }
    }

    // ---- cross-wk reduction (once per segment) ----
    // lsum: reduce over quads; publish per (wq,wk,qc,l16)
#pragma unroll
    for (int qc = 0; qc < 2; ++qc) {
      float vv = lsum[qc];
      vv += __shfl_xor(vv, 16);
      vv += __shfl_xor(vv, 32);
      if (quad == 0) sml[wq][wk][qc][l16] = vv;
    }
    // O partials from wk==1 waves into scratch
    if (wk == 1) {
#pragma unroll
      for (int qc = 0; qc < 2; ++qc)
#pragma unroll
        for (int nb = 0; nb < 4; ++nb)
          red[((wq * 2 + qc) * 4 + nb) * 64 + lane] = oacc[qc][nb];
    }
    __syncthreads();
    if (wk == 0) {
#pragma unroll
      for (int qc = 0; qc < 2; ++qc) {
        const float tot = sml[wq][0][qc][l16] + sml[wq][1][qc][l16];
        const float inv = 1.0f / tot;      // 1/rowsum for q = qc*16 + l16
        float invr[4];
#pragma unroll
        for (int r = 0; r < 4; ++r) invr[r] = __shfl(inv, quad * 4 + r);
#pragma unroll
        for (int nb = 0; nb < 4; ++nb) {
          const f32x4 o2 = red[((wq * 2 + qc) * 4 + nb) * 64 + lane];
#pragma unroll
          for (int r = 0; r < 4; ++r) {
            const int qrow = q0 + wq * 32 + qc * 16 + quad * 4 + r;
            Qb[(size_t)(b * 2048 + qrow) * 1024 + h * 64 + nb * 16 + l16] =
                f2bf((oacc[qc][nb][r] + o2[r]) * invr[r]);
          }
        }
      }
    }
    // next seg's first kt-iteration barrier separates red/sml reads from
    // their next writes; Ks/Vts rewrites are likewise barrier-protected.
  }
}

extern "C" void kernel_launch(void* const* d_in, const int* in_sizes, int n_in,
                              void* d_out, int out_size, void* d_ws, size_t ws_size,
                              hipStream_t stream) {
  const float* q    = (const float*)d_in[0];
  const float* k    = (const float*)d_in[1];
  const float* v    = (const float*)d_in[2];
  const int*   mask = (const int*)d_in[3];
  const float* Wq   = (const float*)d_in[4];
  const float* bq   = (const float*)d_in[5];
  const float* Wk   = (const float*)d_in[6];
  const float* bk   = (const float*)d_in[7];
  const float* Wv   = (const float*)d_in[8];
  const float* bv   = (const float*)d_in[9];
  const float* Wp   = (const float*)d_in[10];
  const float* bp   = (const float*)d_in[11];
  float* out = (float*)d_out;

  char* ws = (char*)d_ws;
  ushort* Qb  = (ushort*)(ws);                      // attn writes X in place
  ushort* Kb  = (ushort*)(ws + (size_t)SZB);
  ushort* Vt  = (ushort*)(ws + (size_t)2 * SZB);
  ushort* Wqb = (ushort*)(ws + (size_t)3 * SZB);
  ushort* Wkb = (ushort*)(ws + (size_t)3 * SZB + WSZ);
  ushort* Wvb = (ushort*)(ws + (size_t)3 * SZB + 2 * WSZ);
  ushort* Wpb = (ushort*)(ws + (size_t)3 * SZB + 3 * WSZ);

  // bf16 input scratch: q,k in d_out (exactly 2*SZB, dead until gemm_proj);
  // v past the 56 MB mark in ws if the workspace is big enough.
  ushort* qb2 = (ushort*)out;
  ushort* kb2 = (ushort*)((char*)out + (size_t)SZB);
  const size_t need_v = (size_t)3 * SZB + 4 * WSZ + SZB;
  const int v_bf = (ws_size >= need_v) ? 1 : 0;
  ushort* vb2 = v_bf ? (ushort*)(ws + (size_t)3 * SZB + 4 * WSZ) : nullptr;

  cvt_w<<<dim3(512, 4), dim3(256), 0, stream>>>(Wq, Wk, Wv, Wp, Wqb, Wkb, Wvb, Wpb);
  cvt_in<<<dim3(4096, 2 + v_bf), dim3(256), 0, stream>>>(q, k, v, qb2, kb2, vb2);
  gemm_qkv8<<<dim3(32, 8, 2 + v_bf), dim3(512), 0, stream>>>(
      qb2, kb2, vb2, Wqb, Wkb, Wvb, bq, bk, bv, Qb, Kb, Vt);
  if (!v_bf)
    gemm_v_fb<<<dim3(64, 8), dim3(256), 0, stream>>>(v, Wvb, bv, Vt);
  attn<<<dim3(16, 64), dim3(256), 0, stream>>>(Qb, Kb, Vt, mask);
  gemm_proj8<<<dim3(32, 8), dim3(512), 0, stream>>>(Qb, Wpb, bp, out);
}

// Round 8
// 298.388 us; speedup vs baseline: 1.0435x; 1.0435x over previous
//
#include <hip/hip_runtime.h>
#include <stdint.h>

// B=4, S=2048, D=1024, H=16, DK=64. fp32 in/out, bf16 MFMA internal.
// Pipeline (5 dispatches):
//   0) cvt_all: {q,k,(v)} + {Wq,Wk,Wv,Wp} fp32 -> bf16 in ONE dispatch.
//   1) gemm_qkv8: 256x128-tile, BK=64, 8-wave, triple-buffered LDS, counted
//      vmcnt(6), T2 XOR-swizzle. XCD-remap: m0=((x&7)*4+(x>>3))*256 -> all 8
//      n0-blocks of an m0 panel land on ONE XCD (A-panel L2 reuse).
//   2) attn: round-6 version (71.4 us): flash causal, XCD-local +
//      causal-balanced, swapped QK^T, fully in-register P (K=16 PV MFMA).
//   3) gemm_proj8: same core + same XCD remap.

#define SZB (8192u * 1024u * 2u)   // one [8192][1024] bf16 buffer (16 MB)
#define WSZ (1024u * 1024u * 2u)   // one [1024][1024] bf16 weight (2 MB)
#define NKT 16                     // K=1024 / BK=64
#define SLOT 24576                 // ushorts per LDS slot: A 16384 + B 8192

typedef __attribute__((ext_vector_type(8))) short  short8;
typedef __attribute__((ext_vector_type(4))) short  short4v;
typedef __attribute__((ext_vector_type(4))) float  f32x4;

#define MFMA16(a, b, c) __builtin_amdgcn_mfma_f32_16x16x32_bf16(a, b, c, 0, 0, 0)

// K=16 MFMA: A/B = 4 bf16 in 2 VGPRs; lane (quad,l16) holds A[m=l16][k=quad*4+j].
__device__ __forceinline__ f32x4 mfma_k16(short4v a, short4v b, f32x4 c) {
#if __has_builtin(__builtin_amdgcn_mfma_f32_16x16x16bf16_1k)
  return __builtin_amdgcn_mfma_f32_16x16x16bf16_1k(a, b, c, 0, 0, 0);
#else
  asm volatile("v_mfma_f32_16x16x16_bf16 %0, %1, %2, %0"
               : "+v"(c) : "v"(a), "v"(b));
  return c;
#endif
}
// pack two f32 -> one u32 of 2 bf16 (lo = a, hi = b), RNE
__device__ __forceinline__ uint32_t cvtpk(float a, float b) {
  uint32_t r;
  asm("v_cvt_pk_bf16_f32 %0, %1, %2" : "=v"(r) : "v"(a), "v"(b));
  return r;
}

__device__ __forceinline__ ushort f2bf(float f) {
  uint32_t u = __float_as_uint(f);
  u += 0x7FFF + ((u >> 16) & 1);   // RNE
  return (ushort)(u >> 16);
}
__device__ __forceinline__ short8 cvt8(float4 a, float4 b) {
  short8 r;
  r[0] = (short)f2bf(a.x); r[1] = (short)f2bf(a.y);
  r[2] = (short)f2bf(a.z); r[3] = (short)f2bf(a.w);
  r[4] = (short)f2bf(b.x); r[5] = (short)f2bf(b.y);
  r[6] = (short)f2bf(b.z); r[7] = (short)f2bf(b.w);
  return r;
}
// async global -> LDS, 16B/lane; LDS dest = wave-uniform base + lane*16
__device__ __forceinline__ void gl_lds16(const ushort* g, ushort* l) {
  __builtin_amdgcn_global_load_lds(
      (__attribute__((address_space(1))) void*)g,
      (__attribute__((address_space(3))) void*)l, 16, 0, 0);
}

// ---------------------------------------------------------------------------
// Fused conversion: z=0:q z=1:k z=2:Wq z=3:Wk z=4:Wv z=5:Wp z=6:v(opt).
// grid (4096, 6 or 7); weight slices use only 512 blocks (early exit).
// ---------------------------------------------------------------------------
__global__ __launch_bounds__(256) void cvt_all(
    const float* __restrict__ q, const float* __restrict__ k,
    const float* __restrict__ v,
    const float* __restrict__ Wq, const float* __restrict__ Wk,
    const float* __restrict__ Wv, const float* __restrict__ Wp,
    ushort* __restrict__ qb2, ushort* __restrict__ kb2,
    ushort* __restrict__ vb2,
    ushort* __restrict__ Wqb, ushort* __restrict__ Wkb,
    ushort* __restrict__ Wvb, ushort* __restrict__ Wpb) {
  const int z = blockIdx.y;
  const bool big = (z == 0) | (z == 1) | (z == 6);
  if (!big && blockIdx.x >= 512) return;
  const float* s = (z == 0) ? q   : (z == 1) ? k   : (z == 2) ? Wq :
                   (z == 3) ? Wk  : (z == 4) ? Wv  : (z == 5) ? Wp : v;
  ushort* d      = (z == 0) ? qb2 : (z == 1) ? kb2 : (z == 2) ? Wqb :
                   (z == 3) ? Wkb : (z == 4) ? Wvb : (z == 5) ? Wpb : vb2;
  const size_t i = (size_t)(blockIdx.x * 256 + threadIdx.x) * 8;
  *(short8*)&d[i] = cvt8(*(const float4*)&s[i], *(const float4*)&s[i + 4]);
}

// ---------------------------------------------------------------------------
// 8-wave triple-buffered core: C = A[M,K]bf16 * W[N,K]bf16^T.
// BM=256, BN=128, BK=64. 512 threads = 8 waves as 4M x 2N; per-wave 64x64.
// XOR-swizzled LDS (linear gl_lds dest, inverse-swizzled global source,
// swizzled ds_read). Schedule per K-tile: {vmcnt(6); barrier; stage(j+2);
// compute} -- counted vmcnt, never 0 in-loop.
// ---------------------------------------------------------------------------
__device__ __forceinline__ void core8p(
    const ushort* __restrict__ A, const ushort* __restrict__ Wb,
    ushort* lds, int m0, int n0, f32x4 acc[4][4]) {
  const int tid  = threadIdx.x;
  const int w    = tid >> 6;
  const int lane = tid & 63;
  const int quad = lane >> 4;
  const int l16  = lane & 15;
  const int wm   = (w >> 1) * 64;   // 4 M-waves
  const int wn   = (w & 1) * 64;    // 2 N-waves

  const ushort* asrc[4];
  const ushort* bsrc[2];
#pragma unroll
  for (int i = 0; i < 4; ++i) {
    const int c = tid + 512 * i;
    asrc[i] = A + (size_t)(m0 + (c >> 3)) * 1024 + ((c & 7) ^ ((c >> 3) & 7)) * 8;
  }
#pragma unroll
  for (int i = 0; i < 2; ++i) {
    const int c = tid + 512 * i;
    bsrc[i] = Wb + (size_t)(n0 + (c >> 3)) * 1024 + ((c & 7) ^ ((c >> 3) & 7)) * 8;
  }

  auto stage = [&](int j, int s) {
    ushort* base = lds + s * SLOT + w * 512;
#pragma unroll
    for (int i = 0; i < 4; ++i)
      gl_lds16(asrc[i] + j * 64, base + i * 4096);
#pragma unroll
    for (int i = 0; i < 2; ++i)
      gl_lds16(bsrc[i] + j * 64, base + 16384 + i * 4096);
  };

  const int rsw = (l16 & 7) * 8;   // read-side XOR (row&7 == l16&7 here)
  auto compute = [&](int s) {
    const ushort* pA = lds + s * SLOT;
    const ushort* pB = pA + 16384;
    short8 a[4][2], b[4][2];
#pragma unroll
    for (int f = 0; f < 4; ++f)
#pragma unroll
      for (int ks = 0; ks < 2; ++ks) {
        a[f][ks] = *(const short8*)&pA[(wm + f * 16 + l16) * 64 +
                                       ((ks * 32 + quad * 8) ^ rsw)];
        b[f][ks] = *(const short8*)&pB[(wn + f * 16 + l16) * 64 +
                                       ((ks * 32 + quad * 8) ^ rsw)];
      }
    __builtin_amdgcn_s_setprio(1);
#pragma unroll
    for (int i = 0; i < 4; ++i)
#pragma unroll
      for (int j2 = 0; j2 < 4; ++j2) {
        acc[i][j2] = MFMA16(a[i][0], b[j2][0], acc[i][j2]);
        acc[i][j2] = MFMA16(a[i][1], b[j2][1], acc[i][j2]);
      }
    __builtin_amdgcn_s_setprio(0);
  };

  stage(0, 0);
  stage(1, 1);
  int s = 0;
#pragma unroll 1
  for (int j = 0; j < NKT - 1; ++j) {
    asm volatile("s_waitcnt vmcnt(6)" ::: "memory");
    __builtin_amdgcn_s_barrier();
    __builtin_amdgcn_sched_barrier(0);
    if (j < NKT - 2) {
      int s2 = s + 2; if (s2 >= 3) s2 -= 3;
      stage(j + 2, s2);
    }
    compute(s);
    if (++s == 3) s = 0;
  }
  asm volatile("s_waitcnt vmcnt(0)" ::: "memory");
  __builtin_amdgcn_s_barrier();
  __builtin_amdgcn_sched_barrier(0);
  compute(s);
}

// XCD remap for (32,8) tile grids: round-robin dispatch gives xcd = x&7;
// m0 index = (x&7)*4 + (x>>3) keeps all 8 n0-blocks of an m0 panel on one
// XCD (A-panel stays L2-resident; bijective on x).
__device__ __forceinline__ void xcd_map(int& m0, int& n0) {
  const int x = (int)blockIdx.x;
  m0 = ((x & 7) * 4 + (x >> 3)) * 256;
  n0 = (int)blockIdx.y * 128;
}

// ---------------------------------------------------------------------------
// QKV projection, pipelined core. grid (32, 8, 3 or 2), 512 threads.
// z==0 -> Qb (pre-scaled by 0.125*log2e), z==1 -> Kb, z==2 -> Vt transposed.
// ---------------------------------------------------------------------------
__global__ __launch_bounds__(512, 2) void gemm_qkv8(
    const ushort* __restrict__ qb2, const ushort* __restrict__ kb2,
    const ushort* __restrict__ vb2,
    const ushort* __restrict__ Wqb, const ushort* __restrict__ Wkb,
    const ushort* __restrict__ Wvb,
    const float* __restrict__ bq, const float* __restrict__ bk,
    const float* __restrict__ bv,
    ushort* __restrict__ Qb, ushort* __restrict__ Kb, ushort* __restrict__ Vt) {
  __shared__ ushort lds[3 * SLOT];   // 144 KB

  const int z = blockIdx.z;
  const ushort* A    = (z == 0) ? qb2 : (z == 1) ? kb2 : vb2;
  const ushort* W    = (z == 0) ? Wqb : (z == 1) ? Wkb : Wvb;
  const float*  bias = (z == 0) ? bq  : (z == 1) ? bk  : bv;

  int m0, n0;
  xcd_map(m0, n0);

  f32x4 acc[4][4] = {};
  core8p(A, W, lds, m0, n0, acc);

  const int tid  = threadIdx.x;
  const int w    = tid >> 6;
  const int lane = tid & 63;
  const int quad = lane >> 4;
  const int l16  = lane & 15;
  const int wm   = (w >> 1) * 64;
  const int wn   = (w & 1) * 64;

  float bvv[4];
#pragma unroll
  for (int j = 0; j < 4; ++j) bvv[j] = bias[n0 + wn + j * 16 + l16];

  if (z < 2) {
    ushort* Out = (z == 0) ? Qb : Kb;
    const float sc = (z == 0) ? 0.1803368801f : 1.0f;  // 0.125*log2(e) for Q
#pragma unroll
    for (int i = 0; i < 4; ++i) {
      const int m = m0 + wm + i * 16 + quad * 4;
#pragma unroll
      for (int j = 0; j < 4; ++j) {
        const int n = n0 + wn + j * 16 + l16;
#pragma unroll
        for (int r = 0; r < 4; ++r)
          Out[(size_t)(m + r) * 1024 + n] = f2bf((acc[i][j][r] + bvv[j]) * sc);
      }
    }
  } else {
#pragma unroll
    for (int i = 0; i < 4; ++i) {
      const int mrow = m0 + wm + i * 16 + quad * 4;
      const int bb   = mrow >> 11;
      const int s0   = mrow & 2047;
#pragma unroll
      for (int j = 0; j < 4; ++j) {
        const int n = n0 + wn + j * 16 + l16;        // n = h*64 + dk
        ushort4 pk;
        pk.x = f2bf(acc[i][j][0] + bvv[j]);
        pk.y = f2bf(acc[i][j][1] + bvv[j]);
        pk.z = f2bf(acc[i][j][2] + bvv[j]);
        pk.w = f2bf(acc[i][j][3] + bvv[j]);
        *(ushort4*)&Vt[(size_t)((bb * 16 + (n >> 6)) * 64 + (n & 63)) * 2048 + s0] = pk;
      }
    }
  }
}

// ---------------------------------------------------------------------------
// Output projection, pipelined core: out = X @ Wp^T + bp, fp32. grid (32, 8).
// ---------------------------------------------------------------------------
__global__ __launch_bounds__(512, 2) void gemm_proj8(
    const ushort* __restrict__ Xin, const ushort* __restrict__ Wpb,
    const float* __restrict__ bp, float* __restrict__ Out) {
  __shared__ ushort lds[3 * SLOT];

  int m0, n0;
  xcd_map(m0, n0);

  f32x4 acc[4][4] = {};
  core8p(Xin, Wpb, lds, m0, n0, acc);

  const int tid  = threadIdx.x;
  const int w    = tid >> 6;
  const int lane = tid & 63;
  const int quad = lane >> 4;
  const int l16  = lane & 15;
  const int wm   = (w >> 1) * 64;
  const int wn   = (w & 1) * 64;

  float bvv[4];
#pragma unroll
  for (int j = 0; j < 4; ++j) bvv[j] = bp[n0 + wn + j * 16 + l16];

#pragma unroll
  for (int i = 0; i < 4; ++i) {
    const int m = m0 + wm + i * 16 + quad * 4;
#pragma unroll
    for (int j = 0; j < 4; ++j) {
      const int n = n0 + wn + j * 16 + l16;
#pragma unroll
      for (int r = 0; r < 4; ++r)
        Out[(size_t)(m + r) * 1024 + n] = acc[i][j][r] + bvv[j];
    }
  }
}

// ---------------------------------------------------------------------------
// Fallback V projection (mixed fp32 core), used only when ws can't hold vb2.
// ---------------------------------------------------------------------------
__global__ __launch_bounds__(256) void gemm_v_fb(
    const float* __restrict__ vin, const ushort* __restrict__ Wvb,
    const float* __restrict__ bv, ushort* __restrict__ Vt) {
  __shared__ ushort As[128 * 32];
  __shared__ ushort Bs[128 * 32];

  const int tid  = threadIdx.x;
  const int w    = tid >> 6;
  const int lane = tid & 63;
  const int quad = lane >> 4;
  const int l16  = lane & 15;
  const int wm   = (w >> 1) * 64;
  const int wn   = (w & 1) * 64;
  const int r0   = tid >> 2;
  const int r1   = r0 + 64;
  const int c0   = (tid & 3) * 8;

  const int m0 = blockIdx.x * 128;
  const int n0 = blockIdx.y * 128;

  f32x4 acc[4][4] = {};
  const ushort* Wg = Wvb + (size_t)(n0 + w * 32 + (lane >> 2)) * 1024 + (lane & 3) * 8;
  const float*  Ag0 = vin + (size_t)(m0 + r0) * 1024 + c0;
  const float*  Ag1 = vin + (size_t)(m0 + r1) * 1024 + c0;

  float4 p0a = *(const float4*)(Ag0), p0b = *(const float4*)(Ag0 + 4);
  float4 p1a = *(const float4*)(Ag1), p1b = *(const float4*)(Ag1 + 4);

  for (int kt = 0; kt < 32; ++kt) {
    const int ko = kt * 32;
    __syncthreads();
    *(short8*)&As[r0 * 32 + c0] = cvt8(p0a, p0b);
    *(short8*)&As[r1 * 32 + c0] = cvt8(p1a, p1b);
    gl_lds16(Wg + ko,         &Bs[(w * 32) * 32]);
    gl_lds16(Wg + 16384 + ko, &Bs[(w * 32 + 16) * 32]);
    __syncthreads();
    if (kt < 31) {
      const int kn = ko + 32;
      p0a = *(const float4*)(Ag0 + kn); p0b = *(const float4*)(Ag0 + kn + 4);
      p1a = *(const float4*)(Ag1 + kn); p1b = *(const float4*)(Ag1 + kn + 4);
    }
    short8 af[4], bfr[4];
#pragma unroll
    for (int i = 0; i < 4; ++i)
      af[i] = *(const short8*)&As[(wm + i * 16 + l16) * 32 + quad * 8];
#pragma unroll
    for (int i = 0; i < 4; ++i)
      bfr[i] = *(const short8*)&Bs[(wn + i * 16 + l16) * 32 + quad * 8];
#pragma unroll
    for (int i = 0; i < 4; ++i)
#pragma unroll
      for (int j = 0; j < 4; ++j)
        acc[i][j] = MFMA16(af[i], bfr[j], acc[i][j]);
  }

  float bvv[4];
#pragma unroll
  for (int j = 0; j < 4; ++j) bvv[j] = bv[n0 + wn + j * 16 + l16];
#pragma unroll
  for (int i = 0; i < 4; ++i) {
    const int mrow = m0 + wm + i * 16 + quad * 4;
    const int bb   = mrow >> 11;
    const int s0   = mrow & 2047;
#pragma unroll
    for (int j = 0; j < 4; ++j) {
      const int n = n0 + wn + j * 16 + l16;
      ushort4 pk;
      pk.x = f2bf(acc[i][j][0] + bvv[j]);
      pk.y = f2bf(acc[i][j][1] + bvv[j]);
      pk.z = f2bf(acc[i][j][2] + bvv[j]);
      pk.w = f2bf(acc[i][j][3] + bvv[j]);
      *(ushort4*)&Vt[(size_t)((bb * 16 + (n >> 6)) * 64 + (n & 63)) * 2048 + s0] = pk;
    }
  }
}

// ---------------------------------------------------------------------------
// Flash attention (causal + padding mask). grid (16 pair, 64 bh), 4 waves.
// ROUND-6 VERSION (measured 71.4 us). XCD-local remap (all 16 blocks of a bh
// on one XCD; its 8-bh K+V set fits the 4 MB per-XCD L2) + causal balance
// (block pair does q-tiles pair and 31-pair -> 33 K-tiles total).
// SWAPPED QK^T: sc = mfma(K,Q) -> lane (quad,l16) holds
//   S[key=nj*16+quad*4+r][q=w*16+l16] -- exactly the K=16 A-frag layout, so
// P feeds PV fully in-register via 8 cvt_pk (no Ps LDS round-trip).
// Padding mask: one load/lane + __ballot, all-ones fast path.
// ---------------------------------------------------------------------------
__global__ __launch_bounds__(256, 4) void attn(
    ushort* __restrict__ Qb, const ushort* __restrict__ Kb,
    const ushort* __restrict__ Vt, const int* __restrict__ mask) {
  __shared__ ushort Ks[64 * 68];         // [key][dk], padded
  __shared__ ushort Vts[64 * 68];        // [dk][key], padded

  const int wgid = (int)blockIdx.x + 16 * (int)blockIdx.y;
  const int xcd  = wgid & 7;
  const int idx  = wgid >> 3;            // 0..127
  const int bh   = xcd * 8 + (idx >> 4); // 8 bh per XCD
  const int pair = idx & 15;
  const int b = bh >> 4, h = bh & 15;
  const int tid = threadIdx.x, w = tid >> 6, lane = tid & 63;
  const int quad = lane >> 4, l16 = lane & 15;
  const int ql = w * 16 + l16;           // local q row (within the 64-tile)

  short8 kst[2], vst[2];
  int mld;

  auto ld_tile = [&](int k0) {
#pragma unroll
    for (int i = 0; i < 2; ++i) {
      const int c = tid + 256 * i;
      kst[i] = *(const short8*)&Kb[(size_t)(b * 2048 + k0 + (c >> 3)) * 1024 +
                                   h * 64 + (c & 7) * 8];
      vst[i] = *(const short8*)&Vt[(size_t)(bh * 64 + (c >> 3)) * 2048 +
                                   k0 + (c & 7) * 8];
    }
    mld = mask[b * 2048 + k0 + lane];
  };

#pragma unroll 1
  for (int seg = 0; seg < 2; ++seg) {
    const int qt = seg ? (31 - pair) : pair;
    const int q0 = qt * 64;

    // Q fragments (B operand): row = q0 + w*16 + l16, k = quad*8 + j (+32)
    const size_t qoff = (size_t)(b * 2048 + q0 + w * 16 + l16) * 1024 + h * 64 + quad * 8;
    const short8 qf0 = *(const short8*)&Qb[qoff];
    const short8 qf1 = *(const short8*)&Qb[qoff + 32];

    f32x4 oacc[4] = {};
    float lsum[4] = {0.f, 0.f, 0.f, 0.f};

    ld_tile(0);

    for (int kt = 0; kt <= qt; ++kt) {
      __syncthreads();   // prior iteration's Ks/Vts readers done
#pragma unroll
      for (int i = 0; i < 2; ++i) {
        const int c = tid + 256 * i;
        *(short8*)&Ks[(c >> 3) * 68 + (c & 7) * 8]  = kst[i];
        *(short8*)&Vts[(c >> 3) * 68 + (c & 7) * 8] = vst[i];
      }
      const int mcur = mld;
      __syncthreads();   // staging visible

      // prefetch next K/V tile: latency hides under QK^T + softmax + PV
      if (kt < qt) ld_tile((kt + 1) * 64);

      const unsigned long long mbits = __ballot(mcur != 0);
      const bool allm = (mbits == ~0ull);

      // scores, SWAPPED: sc[nj][r] = S[key=nj*16+quad*4+r][q=ql]
      f32x4 sc[4];
#pragma unroll
      for (int nj = 0; nj < 4; ++nj) {
        f32x4 z4 = {0.f, 0.f, 0.f, 0.f};
        const short8 kf0 = *(const short8*)&Ks[(nj * 16 + l16) * 68 + quad * 8];
        const short8 kf1 = *(const short8*)&Ks[(nj * 16 + l16) * 68 + 32 + quad * 8];
        z4 = MFMA16(kf0, qf0, z4);
        z4 = MFMA16(kf1, qf1, z4);
        sc[nj] = z4;
      }

      // softmax numerators, in-register
      float pv[4][4];
      if (kt < qt) {
        if (allm) {
#pragma unroll
          for (int nj = 0; nj < 4; ++nj)
#pragma unroll
            for (int r = 0; r < 4; ++r)
              pv[nj][r] = __builtin_amdgcn_exp2f(sc[nj][r]);
        } else {
#pragma unroll
          for (int nj = 0; nj < 4; ++nj) {
            const uint32_t sub = (uint32_t)(mbits >> (nj * 16));
#pragma unroll
            for (int r = 0; r < 4; ++r) {
              const bool ok = (sub >> (quad * 4 + r)) & 1;
              pv[nj][r] = __builtin_amdgcn_exp2f(ok ? sc[nj][r] : -1e5f);
            }
          }
        }
      } else {
#pragma unroll
        for (int nj = 0; nj < 4; ++nj) {
          const uint32_t sub = allm ? 0xffffffffu : (uint32_t)(mbits >> (nj * 16));
#pragma unroll
          for (int r = 0; r < 4; ++r) {
            const int kl = nj * 16 + quad * 4 + r;   // local key
            const bool ok = ((sub >> (quad * 4 + r)) & 1) && (kl <= ql);
            pv[nj][r] = __builtin_amdgcn_exp2f(ok ? sc[nj][r] : -1e5f);
          }
        }
      }
#pragma unroll
      for (int nj = 0; nj < 4; ++nj)
#pragma unroll
        for (int r = 0; r < 4; ++r) lsum[r] += pv[nj][r];

      // P -> bf16 A-frags for K=16 MFMA: pa[nj] elem j = P[key=nj*16+quad*4+j]
      short4v pa[4];
#pragma unroll
      for (int nj = 0; nj < 4; ++nj) {
        uint32_t u0 = cvtpk(pv[nj][0], pv[nj][1]);
        uint32_t u1 = cvtpk(pv[nj][2], pv[nj][3]);
        pa[nj][0] = (short)(u0 & 0xffff); pa[nj][1] = (short)(u0 >> 16);
        pa[nj][2] = (short)(u1 & 0xffff); pa[nj][3] = (short)(u1 >> 16);
      }

      // O += P.V  (16 x mfma 16x16x16; B-frag = V^T[dk=nb*16+l16][key quad*4+j])
#pragma unroll
      for (int nj = 0; nj < 4; ++nj)
#pragma unroll
        for (int nb = 0; nb < 4; ++nb) {
          const short4v vf = *(const short4v*)&Vts[(nb * 16 + l16) * 68 +
                                                   nj * 16 + quad * 4];
          oacc[nb] = mfma_k16(pa[nj], vf, oacc[nb]);
        }
    }

    // lsum: per-lane partials cover q=l16, keys {quad,nj,r}; reduce over quads
    float v = lsum[0] + lsum[1] + lsum[2] + lsum[3];
    v += __shfl_xor(v, 16);
    v += __shfl_xor(v, 32);
    const float inv = 1.0f / v;          // every lane: 1/rowsum for q=l16
    float invr[4];
#pragma unroll
    for (int r = 0; r < 4; ++r) invr[r] = __shfl(inv, quad * 4 + r);

#pragma unroll
    for (int nb = 0; nb < 4; ++nb)
#pragma unroll
      for (int r = 0; r < 4; ++r) {
        const int q = q0 + w * 16 + quad * 4 + r;
        Qb[(size_t)(b * 2048 + q) * 1024 + h * 64 + nb * 16 + l16] =
            f2bf(oacc[nb][r] * invr[r]);
      }
  }
}

extern "C" void kernel_launch(void* const* d_in, const int* in_sizes, int n_in,
                              void* d_out, int out_size, void* d_ws, size_t ws_size,
                              hipStream_t stream) {
  const float* q    = (const float*)d_in[0];
  const float* k    = (const float*)d_in[1];
  const float* v    = (const float*)d_in[2];
  const int*   mask = (const int*)d_in[3];
  const float* Wq   = (const float*)d_in[4];
  const float* bq   = (const float*)d_in[5];
  const float* Wk   = (const float*)d_in[6];
  const float* bk   = (const float*)d_in[7];
  const float* Wv   = (const float*)d_in[8];
  const float* bv   = (const float*)d_in[9];
  const float* Wp   = (const float*)d_in[10];
  const float* bp   = (const float*)d_in[11];
  float* out = (float*)d_out;

  char* ws = (char*)d_ws;
  ushort* Qb  = (ushort*)(ws);                      // attn writes X in place
  ushort* Kb  = (ushort*)(ws + (size_t)SZB);
  ushort* Vt  = (ushort*)(ws + (size_t)2 * SZB);
  ushort* Wqb = (ushort*)(ws + (size_t)3 * SZB);
  ushort* Wkb = (ushort*)(ws + (size_t)3 * SZB + WSZ);
  ushort* Wvb = (ushort*)(ws + (size_t)3 * SZB + 2 * WSZ);
  ushort* Wpb = (ushort*)(ws + (size_t)3 * SZB + 3 * WSZ);

  // bf16 input scratch: q,k in d_out (exactly 2*SZB, dead until gemm_proj);
  // v past the 56 MB mark in ws if the workspace is big enough.
  ushort* qb2 = (ushort*)out;
  ushort* kb2 = (ushort*)((char*)out + (size_t)SZB);
  const size_t need_v = (size_t)3 * SZB + 4 * WSZ + SZB;
  const int v_bf = (ws_size >= need_v) ? 1 : 0;
  ushort* vb2 = v_bf ? (ushort*)(ws + (size_t)3 * SZB + 4 * WSZ) : nullptr;

  cvt_all<<<dim3(4096, 6 + v_bf), dim3(256), 0, stream>>>(
      q, k, v, Wq, Wk, Wv, Wp, qb2, kb2, vb2, Wqb, Wkb, Wvb, Wpb);
  gemm_qkv8<<<dim3(32, 8, 2 + v_bf), dim3(512), 0, stream>>>(
      qb2, kb2, vb2, Wqb, Wkb, Wvb, bq, bk, bv, Qb, Kb, Vt);
  if (!v_bf)
    gemm_v_fb<<<dim3(64, 8), dim3(256), 0, stream>>>(v, Wvb, bv, Vt);
  attn<<<dim3(16, 64), dim3(256), 0, stream>>>(Qb, Kb, Vt, mask);
  gemm_proj8<<<dim3(32, 8), dim3(512), 0, stream>>>(Qb, Wpb, bp, out);
}